// Round 5
// baseline (267.657 us; speedup 1.0000x reference)
//
#include <hip/hip_runtime.h>

#define NB 32
#define NS 2048
#define NH 1024
#define WIN 15   // exp(sc-lse-0.5*d^2): score-lse<=0 -> |d|>15 underflows to 0.0f (matches ref)

// ---------------- K1: v[b,h] = sum_d dec[b,d]*Wa[d,h]; zero denomD/done.
// grid = 16 ht * 32 b (b fastest -> 32 co-scheduled blocks share one 256KB Wa tile in L2)
__global__ __launch_bounds__(256) void k1_v(const float* __restrict__ dec,
                                            const float* __restrict__ Wa,
                                            float* __restrict__ v,
                                            double* __restrict__ denomD,
                                            int* __restrict__ done) {
    __shared__ float red[256];
    int blk = blockIdx.x;
    int b = blk & 31, ht = blk >> 5;
    int t = threadIdx.x;
    if (blk == 0 && t < NB) { denomD[t] = 0.0; done[t] = 0; }

    int ds = t >> 6, hl = t & 63;
    int h = ht * 64 + hl;
    const float* decb = dec + b * NH + ds * 256;
    const float* wa   = Wa + (size_t)(ds * 256) * NH + h;
    float a0 = 0.f, a1 = 0.f, a2 = 0.f, a3 = 0.f;
#pragma unroll 2
    for (int d = 0; d < 256; d += 4) {             // 4 split accumulators: no dep chain
        a0 = fmaf(decb[d],     wa[(size_t)d * NH],       a0);
        a1 = fmaf(decb[d + 1], wa[(size_t)(d + 1) * NH], a1);
        a2 = fmaf(decb[d + 2], wa[(size_t)(d + 2) * NH], a2);
        a3 = fmaf(decb[d + 3], wa[(size_t)(d + 3) * NH], a3);
    }
    red[t] = (a0 + a1) + (a2 + a3);
    __syncthreads();
    if (t < 64)
        v[b * NH + ht * 64 + t] = red[t] + red[t + 64] + red[t + 128] + red[t + 192];
}

// ---------------- K2: fused scores + denom + last-block-per-b epilogue (attn + ctx).
// Hot loop identical to round 4: v in 16 registers, 4 rows/wave, 16 rows/block,
// 4096 blocks (128 per b). Winner block (done[b]==127) computes attn + windowed ctx.
__global__ __launch_bounds__(256) void k2_fused(const float* __restrict__ enc,
                                                const float* __restrict__ v,
                                                const int* __restrict__ ts,
                                                float* __restrict__ scores,
                                                double* __restrict__ denomD,
                                                int* __restrict__ done,
                                                float* __restrict__ ctx,
                                                float* __restrict__ attn) {
    __shared__ float vs[NH];
    __shared__ float rowsc[16];
    __shared__ int winner;
    int t = threadIdx.x, wid = t >> 6, lane = t & 63;
    int b = blockIdx.x >> 7;           // 128 blocks per b
    int row0 = blockIdx.x << 4;        // global row (b*NS + s)

    ((float4*)vs)[t] = ((const float4*)(v + b * NH))[t];
    __syncthreads();
    const float4* vv = (const float4*)vs;
    float4 vr0 = vv[lane], vr1 = vv[64 + lane], vr2 = vv[128 + lane], vr3 = vv[192 + lane];

    int r0 = row0 + wid * 4;
    const float4* eb = (const float4*)(enc + (size_t)r0 * NH);
    float acc[4];
#pragma unroll
    for (int r = 0; r < 4; ++r) {
        float4 x0 = eb[r * 256 + lane];
        float4 x1 = eb[r * 256 + 64 + lane];
        float4 x2 = eb[r * 256 + 128 + lane];
        float4 x3 = eb[r * 256 + 192 + lane];
        float s = 0.f;
        s = fmaf(x0.x, vr0.x, s); s = fmaf(x0.y, vr0.y, s);
        s = fmaf(x0.z, vr0.z, s); s = fmaf(x0.w, vr0.w, s);
        s = fmaf(x1.x, vr1.x, s); s = fmaf(x1.y, vr1.y, s);
        s = fmaf(x1.z, vr1.z, s); s = fmaf(x1.w, vr1.w, s);
        s = fmaf(x2.x, vr2.x, s); s = fmaf(x2.y, vr2.y, s);
        s = fmaf(x2.z, vr2.z, s); s = fmaf(x2.w, vr2.w, s);
        s = fmaf(x3.x, vr3.x, s); s = fmaf(x3.y, vr3.y, s);
        s = fmaf(x3.z, vr3.z, s); s = fmaf(x3.w, vr3.w, s);
        acc[r] = s;
    }
#pragma unroll
    for (int r = 0; r < 4; ++r) {
        float s = acc[r];
#pragma unroll
        for (int off = 32; off >= 1; off >>= 1) s += __shfl_xor(s, off, 64);
        if (lane == 0) { scores[r0 + r] = s; rowsc[wid * 4 + r] = s; }
    }
    __syncthreads();

    // ---- 16 row-partials -> one f64 atomic; arrive on done[b] ----
    if (t < 16) {
        double e = exp((double)rowsc[t]);
#pragma unroll
        for (int off = 8; off >= 1; off >>= 1) e += __shfl_xor(e, off, 64);
        if (t == 0) {
            atomicAdd(&denomD[b], e);
            __threadfence();                    // release: scores + denom visible device-wide
            int old = atomicAdd(&done[b], 1);
            winner = (old == 127) ? 1 : 0;
        }
    }
    __syncthreads();

    // ---- last block of this b: attn for all S + windowed ctx (direct store) ----
    if (winner) {
        __threadfence();                        // acquire
        float lse = (float)log(denomD[b]);
        int p = ts[b];
        float pf = (float)p;
        const float* sb = scores + (size_t)b * NS;
#pragma unroll
        for (int k = 0; k < 8; ++k) {
            int s = t + 256 * k;
            float d = (float)s - pf;
            attn[(size_t)b * NS + s] = expf(sb[s] - lse - 0.5f * d * d);
        }
        int w0 = max(0, p - WIN), w1 = min(NS - 1, p + WIN);
        float c0 = 0.f, c1 = 0.f, c2 = 0.f, c3 = 0.f;
        for (int r = w0; r <= w1; ++r) {
            float dr = (float)r - pf;
            float w = expf(sb[r] - lse - 0.5f * dr * dr);
            const float* er = enc + ((size_t)b * NS + r) * NH;
            c0 = fmaf(w, er[t],       c0);
            c1 = fmaf(w, er[t + 256], c1);
            c2 = fmaf(w, er[t + 512], c2);
            c3 = fmaf(w, er[t + 768], c3);
        }
        ctx[b * NH + t]       = c0;
        ctx[b * NH + t + 256] = c1;
        ctx[b * NH + t + 512] = c2;
        ctx[b * NH + t + 768] = c3;
    }
}

extern "C" void kernel_launch(void* const* d_in, const int* in_sizes, int n_in,
                              void* d_out, int out_size, void* d_ws, size_t ws_size,
                              hipStream_t stream) {
    const float* enc  = (const float*)d_in[0];   // [B,S,H]
    const float* dec  = (const float*)d_in[1];   // [B,H]
    const int*   ts   = (const int*)d_in[2];     // [B]
    const float* Wa_w = (const float*)d_in[3];   // [H,H]
    // d_in[4] = Wa_b: uniform per-b score shift -> softmax-invariant, dropped.

    float* out  = (float*)d_out;
    float* ctx  = out;             // [B,H]
    float* attn = out + NB * NH;   // [B,S]

    float*  v      = (float*)d_ws;                  // NB*NH floats
    float*  scores = v + NB * NH;                   // NB*NS floats
    double* denomD = (double*)(scores + NB * NS);   // NB doubles (8B-aligned)
    int*    done   = (int*)(denomD + NB);           // NB ints

    k1_v    <<<512,  256, 0, stream>>>(dec, Wa_w, v, denomD, done);
    k2_fused<<<4096, 256, 0, stream>>>(enc, v, ts, scores, denomD, done, ctx, attn);
}

// Round 6
// 107.048 us; speedup vs baseline: 2.5004x; 2.5004x over previous
//
#include <hip/hip_runtime.h>

#define NB 32
#define NS 2048
#define NH 1024
#define WIN 15   // exp(sc-lse-0.5*d^2): score-lse<=0 -> |d|>15 underflows to 0.0f (matches ref)

// ---------------- K1: v[b,h] = sum_d dec[b,d]*Wa[d,h]; zero denomD and ctx.
// grid = 16 ht * 32 b (b fastest -> 32 co-scheduled blocks share one Wa tile in L2)
__global__ __launch_bounds__(256) void k1_v(const float* __restrict__ dec,
                                            const float* __restrict__ Wa,
                                            float* __restrict__ v,
                                            double* __restrict__ denomD,
                                            float* __restrict__ ctx) {
    __shared__ float red[256];
    int blk = blockIdx.x;
    int b = blk & 31, ht = blk >> 5;
    int t = threadIdx.x;
    if (blk == 0 && t < NB) denomD[t] = 0.0;
    if (blk < 128) ctx[blk * 256 + t] = 0.f;       // NB*NH = 128*256

    int ds = t >> 6, hl = t & 63;
    int h = ht * 64 + hl;
    const float* decb = dec + b * NH + ds * 256;
    const float* wa   = Wa + (size_t)(ds * 256) * NH + h;
    float a0 = 0.f, a1 = 0.f, a2 = 0.f, a3 = 0.f;
#pragma unroll 2
    for (int d = 0; d < 256; d += 4) {             // 4 split accumulators: no dep chain
        a0 = fmaf(decb[d],     wa[(size_t)d * NH],       a0);
        a1 = fmaf(decb[d + 1], wa[(size_t)(d + 1) * NH], a1);
        a2 = fmaf(decb[d + 2], wa[(size_t)(d + 2) * NH], a2);
        a3 = fmaf(decb[d + 3], wa[(size_t)(d + 3) * NH], a3);
    }
    red[t] = (a0 + a1) + (a2 + a3);
    __syncthreads();
    if (t < 64)
        v[b * NH + ht * 64 + t] = red[t] + red[t + 64] + red[t + 128] + red[t + 192];
}

// ---------------- K2: scores[b,s] = enc[b,s,:].v[b,:]; per-wave f64 denom atomic.
// NO LDS, NO barriers: each wave loads v[b] into 16 regs from global (L2-hit),
// then streams 8 rows. 32 rows/block, 2048 blocks (64 per b). VGPR cap 128.
__global__ __launch_bounds__(256, 4) void k2_scores(const float* __restrict__ enc,
                                                    const float* __restrict__ v,
                                                    float* __restrict__ scores,
                                                    double* __restrict__ denomD) {
    int t = threadIdx.x, wid = t >> 6, lane = t & 63;
    int blk = blockIdx.x;
    int b = blk >> 6;                      // 64 blocks per b
    int row0 = (blk << 5) + wid * 8;       // global row (b*NS + s)

    const float4* vb = (const float4*)(v + b * NH);
    float4 vr0 = vb[lane], vr1 = vb[64 + lane], vr2 = vb[128 + lane], vr3 = vb[192 + lane];

    const float4* eb = (const float4*)(enc + (size_t)row0 * NH);
    float acc[8];
#pragma unroll
    for (int r = 0; r < 8; ++r) {
        float4 x0 = eb[r * 256 + lane];
        float4 x1 = eb[r * 256 + 64 + lane];
        float4 x2 = eb[r * 256 + 128 + lane];
        float4 x3 = eb[r * 256 + 192 + lane];
        float s = 0.f;
        s = fmaf(x0.x, vr0.x, s); s = fmaf(x0.y, vr0.y, s);
        s = fmaf(x0.z, vr0.z, s); s = fmaf(x0.w, vr0.w, s);
        s = fmaf(x1.x, vr1.x, s); s = fmaf(x1.y, vr1.y, s);
        s = fmaf(x1.z, vr1.z, s); s = fmaf(x1.w, vr1.w, s);
        s = fmaf(x2.x, vr2.x, s); s = fmaf(x2.y, vr2.y, s);
        s = fmaf(x2.z, vr2.z, s); s = fmaf(x2.w, vr2.w, s);
        s = fmaf(x3.x, vr3.x, s); s = fmaf(x3.y, vr3.y, s);
        s = fmaf(x3.z, vr3.z, s); s = fmaf(x3.w, vr3.w, s);
        acc[r] = s;
    }
#pragma unroll
    for (int r = 0; r < 8; ++r) {
#pragma unroll
        for (int off = 32; off >= 1; off >>= 1) acc[r] += __shfl_xor(acc[r], off, 64);
    }
    if (lane == 0) {
#pragma unroll
        for (int r = 0; r < 8; ++r) scores[row0 + r] = acc[r];
        double e = 0.0;
#pragma unroll
        for (int r = 0; r < 8; ++r) e += exp((double)acc[r]);
        atomicAdd(&denomD[b], e);
    }
}

// ---------------- K3: attn = exp(score - lse - 0.5 d^2); windowed ctx via atomics.
// grid = 32 b * 8 s-chunks
__global__ __launch_bounds__(256) void k3_out(const float* __restrict__ enc,
                                              const float* __restrict__ scores,
                                              const int* __restrict__ ts,
                                              const double* __restrict__ denomD,
                                              float* __restrict__ ctx,
                                              float* __restrict__ attn) {
    int b = blockIdx.x >> 3;
    int c = blockIdx.x & 7;
    int t = threadIdx.x;

    float lse = (float)log(denomD[b]);
    int p = ts[b];
    float pf = (float)p;

    int s = c * 256 + t;
    float sc = scores[b * NS + s];
    float d = (float)s - pf;
    attn[(size_t)b * NS + s] = expf(sc - lse - 0.5f * d * d);

    int w0 = max(0, p - WIN), w1 = min(NS - 1, p + WIN);
    int r0 = max(w0, c * 256), r1 = min(w1, c * 256 + 255);
    if (r0 <= r1) {
        const float* sb = scores + (size_t)b * NS;
        float a0 = 0.f, a1 = 0.f, a2 = 0.f, a3 = 0.f;
        for (int r = r0; r <= r1; ++r) {
            float dr = (float)r - pf;
            float w = expf(sb[r] - lse - 0.5f * dr * dr);
            const float* er = enc + ((size_t)b * NS + r) * NH;
            a0 = fmaf(w, er[t],       a0);
            a1 = fmaf(w, er[t + 256], a1);
            a2 = fmaf(w, er[t + 512], a2);
            a3 = fmaf(w, er[t + 768], a3);
        }
        atomicAdd(&ctx[b * NH + t],       a0);
        atomicAdd(&ctx[b * NH + t + 256], a1);
        atomicAdd(&ctx[b * NH + t + 512], a2);
        atomicAdd(&ctx[b * NH + t + 768], a3);
    }
}

extern "C" void kernel_launch(void* const* d_in, const int* in_sizes, int n_in,
                              void* d_out, int out_size, void* d_ws, size_t ws_size,
                              hipStream_t stream) {
    const float* enc  = (const float*)d_in[0];   // [B,S,H]
    const float* dec  = (const float*)d_in[1];   // [B,H]
    const int*   ts   = (const int*)d_in[2];     // [B]
    const float* Wa_w = (const float*)d_in[3];   // [H,H]
    // d_in[4] = Wa_b: uniform per-b score shift -> softmax-invariant, dropped.

    float* out  = (float*)d_out;
    float* ctx  = out;             // [B,H]
    float* attn = out + NB * NH;   // [B,S]

    float*  v      = (float*)d_ws;                  // NB*NH floats
    float*  scores = v + NB * NH;                   // NB*NS floats
    double* denomD = (double*)(scores + NB * NS);   // NB doubles (8B-aligned)

    k1_v     <<<512,  256, 0, stream>>>(dec, Wa_w, v, denomD, ctx);
    k2_scores<<<2048, 256, 0, stream>>>(enc, v, scores, denomD);
    k3_out   <<<NB*8, 256, 0, stream>>>(enc, scores, ts, denomD, ctx, attn);
}

// Round 7
// 91.004 us; speedup vs baseline: 2.9412x; 1.1763x over previous
//
#include <hip/hip_runtime.h>

#define NB 32
#define NS 2048
#define NH 1024
#define WIN 15   // exp(sc-lse-0.5*d^2): score-lse<=0 -> |d|>15 underflows to 0.0f (matches ref)

typedef float f4 __attribute__((ext_vector_type(4)));

// ---------------- K1: v[b,h] = sum_d dec[b,d]*Wa[d,h]; zero denomD.
// grid = 16 ht * 32 b (b fastest -> 32 co-scheduled blocks share one Wa tile in L2)
__global__ __launch_bounds__(256) void k1_v(const float* __restrict__ dec,
                                            const float* __restrict__ Wa,
                                            float* __restrict__ v,
                                            double* __restrict__ denomD) {
    __shared__ float red[256];
    int blk = blockIdx.x;
    int b = blk & 31, ht = blk >> 5;
    int t = threadIdx.x;
    if (blk == 0 && t < NB) denomD[t] = 0.0;

    int ds = t >> 6, hl = t & 63;
    int h = ht * 64 + hl;
    const float* decb = dec + b * NH + ds * 256;
    const float* wa   = Wa + (size_t)(ds * 256) * NH + h;
    float a0 = 0.f, a1 = 0.f, a2 = 0.f, a3 = 0.f;
#pragma unroll 2
    for (int d = 0; d < 256; d += 4) {             // 4 split accumulators: no dep chain
        a0 = fmaf(decb[d],     wa[(size_t)d * NH],       a0);
        a1 = fmaf(decb[d + 1], wa[(size_t)(d + 1) * NH], a1);
        a2 = fmaf(decb[d + 2], wa[(size_t)(d + 2) * NH], a2);
        a3 = fmaf(decb[d + 3], wa[(size_t)(d + 3) * NH], a3);
    }
    red[t] = (a0 + a1) + (a2 + a3);
    __syncthreads();
    if (t < 64)
        v[b * NH + ht * 64 + t] = red[t] + red[t + 64] + red[t + 128] + red[t + 192];
}

__device__ __forceinline__ float dot16(f4 x0, f4 x1, f4 x2, f4 x3,
                                       float4 v0, float4 v1, float4 v2, float4 v3) {
    float s = 0.f;
    s = fmaf(x0.x, v0.x, s); s = fmaf(x0.y, v0.y, s); s = fmaf(x0.z, v0.z, s); s = fmaf(x0.w, v0.w, s);
    s = fmaf(x1.x, v1.x, s); s = fmaf(x1.y, v1.y, s); s = fmaf(x1.z, v1.z, s); s = fmaf(x1.w, v1.w, s);
    s = fmaf(x2.x, v2.x, s); s = fmaf(x2.y, v2.y, s); s = fmaf(x2.z, v2.z, s); s = fmaf(x2.w, v2.w, s);
    s = fmaf(x3.x, v3.x, s); s = fmaf(x3.y, v3.y, s); s = fmaf(x3.z, v3.z, s); s = fmaf(x3.w, v3.w, s);
    return s;
}

// ---------------- K2: scores[b,s] = enc[b,s,:].v[b,:]; per-block f64 denom atomic.
// Round-4 shape (LDS-staged v -> 16 regs, 4 rows/wave, 16 rows/block, 4096 blocks)
// with 2-row pipelined NON-TEMPORAL loads: 8 dwordx4 in flight steady-state.
__global__ __launch_bounds__(256) void k2_scores(const float* __restrict__ enc,
                                                 const float* __restrict__ v,
                                                 float* __restrict__ scores,
                                                 double* __restrict__ denomD) {
    __shared__ float vs[NH];
    __shared__ float rowsc[16];
    int t = threadIdx.x, wid = t >> 6, lane = t & 63;
    int b = blockIdx.x >> 7;           // 128 blocks per b
    int row0 = blockIdx.x << 4;        // global row (b*NS + s)

    ((float4*)vs)[t] = ((const float4*)(v + b * NH))[t];
    __syncthreads();
    const float4* vv = (const float4*)vs;
    float4 vr0 = vv[lane], vr1 = vv[64 + lane], vr2 = vv[128 + lane], vr3 = vv[192 + lane];

    int r0 = row0 + wid * 4;
    const f4* eb = (const f4*)(enc + (size_t)r0 * NH) + lane;   // rows stride 256 f4

    // 2-row pipeline: rows 0,1 in flight; FMA row0 while row2 loads; etc.
    f4 a0 = __builtin_nontemporal_load(eb);
    f4 a1 = __builtin_nontemporal_load(eb + 64);
    f4 a2 = __builtin_nontemporal_load(eb + 128);
    f4 a3 = __builtin_nontemporal_load(eb + 192);
    f4 b0 = __builtin_nontemporal_load(eb + 256);
    f4 b1 = __builtin_nontemporal_load(eb + 320);
    f4 b2 = __builtin_nontemporal_load(eb + 384);
    f4 b3 = __builtin_nontemporal_load(eb + 448);

    float s0 = dot16(a0, a1, a2, a3, vr0, vr1, vr2, vr3);
    a0 = __builtin_nontemporal_load(eb + 512);
    a1 = __builtin_nontemporal_load(eb + 576);
    a2 = __builtin_nontemporal_load(eb + 640);
    a3 = __builtin_nontemporal_load(eb + 704);
    float s1 = dot16(b0, b1, b2, b3, vr0, vr1, vr2, vr3);
    b0 = __builtin_nontemporal_load(eb + 768);
    b1 = __builtin_nontemporal_load(eb + 832);
    b2 = __builtin_nontemporal_load(eb + 896);
    b3 = __builtin_nontemporal_load(eb + 960);
    float s2 = dot16(a0, a1, a2, a3, vr0, vr1, vr2, vr3);
    float s3 = dot16(b0, b1, b2, b3, vr0, vr1, vr2, vr3);

    float acc[4] = {s0, s1, s2, s3};
#pragma unroll
    for (int r = 0; r < 4; ++r) {
#pragma unroll
        for (int off = 32; off >= 1; off >>= 1) acc[r] += __shfl_xor(acc[r], off, 64);
        if (lane == 0) { scores[r0 + r] = acc[r]; rowsc[wid * 4 + r] = acc[r]; }
    }
    __syncthreads();
    if (t < 16) {                       // 16 row-partials -> one f64 atomic
        double e = exp((double)rowsc[t]);
#pragma unroll
        for (int off = 8; off >= 1; off >>= 1) e += __shfl_xor(e, off, 64);
        if (t == 0) atomicAdd(&denomD[b], e);
    }
}

// ---------------- K3: attn = exp(score - lse - 0.5 d^2); owner-chunk computes whole
// ctx window directly (no atomics, no zero-init). grid = 32 b * 8 s-chunks.
__global__ __launch_bounds__(256) void k3_out(const float* __restrict__ enc,
                                              const float* __restrict__ scores,
                                              const int* __restrict__ ts,
                                              const double* __restrict__ denomD,
                                              float* __restrict__ ctx,
                                              float* __restrict__ attn) {
    int b = blockIdx.x >> 3;
    int c = blockIdx.x & 7;
    int t = threadIdx.x;

    float lse = (float)log(denomD[b]);
    int p = ts[b];
    float pf = (float)p;

    int s = c * 256 + t;
    float sc = scores[b * NS + s];
    float d = (float)s - pf;
    attn[(size_t)b * NS + s] = expf(sc - lse - 0.5f * d * d);

    if ((p >> 8) == c) {               // owner chunk: full window, direct store
        int w0 = max(0, p - WIN), w1 = min(NS - 1, p + WIN);
        const float* sb = scores + (size_t)b * NS;
        float a0 = 0.f, a1 = 0.f, a2 = 0.f, a3 = 0.f;
        for (int r = w0; r <= w1; ++r) {
            float dr = (float)r - pf;
            float w = expf(sb[r] - lse - 0.5f * dr * dr);
            const float* er = enc + ((size_t)b * NS + r) * NH;
            a0 = fmaf(w, er[t],       a0);
            a1 = fmaf(w, er[t + 256], a1);
            a2 = fmaf(w, er[t + 512], a2);
            a3 = fmaf(w, er[t + 768], a3);
        }
        ctx[b * NH + t]       = a0;
        ctx[b * NH + t + 256] = a1;
        ctx[b * NH + t + 512] = a2;
        ctx[b * NH + t + 768] = a3;
    }
}

extern "C" void kernel_launch(void* const* d_in, const int* in_sizes, int n_in,
                              void* d_out, int out_size, void* d_ws, size_t ws_size,
                              hipStream_t stream) {
    const float* enc  = (const float*)d_in[0];   // [B,S,H]
    const float* dec  = (const float*)d_in[1];   // [B,H]
    const int*   ts   = (const int*)d_in[2];     // [B]
    const float* Wa_w = (const float*)d_in[3];   // [H,H]
    // d_in[4] = Wa_b: uniform per-b score shift -> softmax-invariant, dropped.

    float* out  = (float*)d_out;
    float* ctx  = out;             // [B,H]
    float* attn = out + NB * NH;   // [B,S]

    float*  v      = (float*)d_ws;                  // NB*NH floats
    float*  scores = v + NB * NH;                   // NB*NS floats
    double* denomD = (double*)(scores + NB * NS);   // NB doubles (8B-aligned)

    k1_v     <<<512,  256, 0, stream>>>(dec, Wa_w, v, denomD);
    k2_scores<<<4096, 256, 0, stream>>>(enc, v, scores, denomD);
    k3_out   <<<NB*8, 256, 0, stream>>>(enc, scores, ts, denomD, ctx, attn);
}

// Round 8
// 73.267 us; speedup vs baseline: 3.6532x; 1.2421x over previous
//
#include <hip/hip_runtime.h>

#define NB 32
#define NS 2048
#define NH 1024
#define WIN 15   // exp(sc-lse-0.5*d^2): score-lse<=0 -> |d|>15 underflows to 0.0f (matches ref)

// ---------------- K1: v[b,h] = sum_d dec[b,d]*Wa[d,h]; zero denomD.
// grid = 16 ht * 32 b (b fastest -> 32 co-scheduled blocks share one Wa tile in L2)
__global__ __launch_bounds__(256) void k1_v(const float* __restrict__ dec,
                                            const float* __restrict__ Wa,
                                            float* __restrict__ v,
                                            double* __restrict__ denomD) {
    __shared__ float red[256];
    int blk = blockIdx.x;
    int b = blk & 31, ht = blk >> 5;
    int t = threadIdx.x;
    if (blk == 0 && t < NB) denomD[t] = 0.0;

    int ds = t >> 6, hl = t & 63;
    int h = ht * 64 + hl;
    const float* decb = dec + b * NH + ds * 256;
    const float* wa   = Wa + (size_t)(ds * 256) * NH + h;
    float a0 = 0.f, a1 = 0.f, a2 = 0.f, a3 = 0.f;
#pragma unroll 2
    for (int d = 0; d < 256; d += 4) {             // 4 split accumulators: no dep chain
        a0 = fmaf(decb[d],     wa[(size_t)d * NH],       a0);
        a1 = fmaf(decb[d + 1], wa[(size_t)(d + 1) * NH], a1);
        a2 = fmaf(decb[d + 2], wa[(size_t)(d + 2) * NH], a2);
        a3 = fmaf(decb[d + 3], wa[(size_t)(d + 3) * NH], a3);
    }
    red[t] = (a0 + a1) + (a2 + a3);
    __syncthreads();
    if (t < 64)
        v[b * NH + ht * 64 + t] = red[t] + red[t + 64] + red[t + 128] + red[t + 192];
}

// ---------------- K2: scores[b,s] = enc[b,s,:].v[b,:]; per-block f64 denom atomic.
// Round-4 hot loop (LDS-staged v -> 16 regs, 4 rows/wave, row-serial compiler-
// scheduled loads, NO nontemporal). 512 threads/block = 8 waves = 32 rows/block,
// 2048 blocks (64 per b): half the stagings/barriers/atomics of the 256-thr shape.
__global__ __launch_bounds__(512) void k2_scores(const float* __restrict__ enc,
                                                 const float* __restrict__ v,
                                                 float* __restrict__ scores,
                                                 double* __restrict__ denomD) {
    __shared__ float vs[NH];
    __shared__ float rowsc[32];
    int t = threadIdx.x, wid = t >> 6, lane = t & 63;
    int b = blockIdx.x >> 6;           // 64 blocks per b
    int row0 = blockIdx.x << 5;        // global row (b*NS + s)

    if (t < 256) ((float4*)vs)[t] = ((const float4*)(v + b * NH))[t];
    __syncthreads();
    const float4* vv = (const float4*)vs;
    float4 vr0 = vv[lane], vr1 = vv[64 + lane], vr2 = vv[128 + lane], vr3 = vv[192 + lane];

    int r0 = row0 + wid * 4;
    const float4* eb = (const float4*)(enc + (size_t)r0 * NH);
    float acc[4];
#pragma unroll
    for (int r = 0; r < 4; ++r) {
        float4 x0 = eb[r * 256 + lane];
        float4 x1 = eb[r * 256 + 64 + lane];
        float4 x2 = eb[r * 256 + 128 + lane];
        float4 x3 = eb[r * 256 + 192 + lane];
        float s = 0.f;
        s = fmaf(x0.x, vr0.x, s); s = fmaf(x0.y, vr0.y, s);
        s = fmaf(x0.z, vr0.z, s); s = fmaf(x0.w, vr0.w, s);
        s = fmaf(x1.x, vr1.x, s); s = fmaf(x1.y, vr1.y, s);
        s = fmaf(x1.z, vr1.z, s); s = fmaf(x1.w, vr1.w, s);
        s = fmaf(x2.x, vr2.x, s); s = fmaf(x2.y, vr2.y, s);
        s = fmaf(x2.z, vr2.z, s); s = fmaf(x2.w, vr2.w, s);
        s = fmaf(x3.x, vr3.x, s); s = fmaf(x3.y, vr3.y, s);
        s = fmaf(x3.z, vr3.z, s); s = fmaf(x3.w, vr3.w, s);
        acc[r] = s;
    }
#pragma unroll
    for (int r = 0; r < 4; ++r) {
#pragma unroll
        for (int off = 32; off >= 1; off >>= 1) acc[r] += __shfl_xor(acc[r], off, 64);
        if (lane == 0) { scores[r0 + r] = acc[r]; rowsc[wid * 4 + r] = acc[r]; }
    }
    __syncthreads();
    if (t < 32) {                       // 32 row-partials (wave 0) -> one f64 atomic
        double e = exp((double)rowsc[t]);
#pragma unroll
        for (int off = 16; off >= 1; off >>= 1) e += __shfl_xor(e, off, 64);
        if (t == 0) atomicAdd(&denomD[b], e);
    }
}

// ---------------- K3: attn = exp(score - lse - 0.5 d^2); owner-chunk computes whole
// ctx window directly (no atomics, no zero-init). grid = 32 b * 8 s-chunks.
__global__ __launch_bounds__(256) void k3_out(const float* __restrict__ enc,
                                              const float* __restrict__ scores,
                                              const int* __restrict__ ts,
                                              const double* __restrict__ denomD,
                                              float* __restrict__ ctx,
                                              float* __restrict__ attn) {
    int b = blockIdx.x >> 3;
    int c = blockIdx.x & 7;
    int t = threadIdx.x;

    float lse = (float)log(denomD[b]);
    int p = ts[b];
    float pf = (float)p;

    int s = c * 256 + t;
    float sc = scores[b * NS + s];
    float d = (float)s - pf;
    attn[(size_t)b * NS + s] = expf(sc - lse - 0.5f * d * d);

    if ((p >> 8) == c) {               // owner chunk: full window, direct store
        int w0 = max(0, p - WIN), w1 = min(NS - 1, p + WIN);
        const float* sb = scores + (size_t)b * NS;
        float a0 = 0.f, a1 = 0.f, a2 = 0.f, a3 = 0.f;
        for (int r = w0; r <= w1; ++r) {
            float dr = (float)r - pf;
            float w = expf(sb[r] - lse - 0.5f * dr * dr);
            const float* er = enc + ((size_t)b * NS + r) * NH;
            a0 = fmaf(w, er[t],       a0);
            a1 = fmaf(w, er[t + 256], a1);
            a2 = fmaf(w, er[t + 512], a2);
            a3 = fmaf(w, er[t + 768], a3);
        }
        ctx[b * NH + t]       = a0;
        ctx[b * NH + t + 256] = a1;
        ctx[b * NH + t + 512] = a2;
        ctx[b * NH + t + 768] = a3;
    }
}

extern "C" void kernel_launch(void* const* d_in, const int* in_sizes, int n_in,
                              void* d_out, int out_size, void* d_ws, size_t ws_size,
                              hipStream_t stream) {
    const float* enc  = (const float*)d_in[0];   // [B,S,H]
    const float* dec  = (const float*)d_in[1];   // [B,H]
    const int*   ts   = (const int*)d_in[2];     // [B]
    const float* Wa_w = (const float*)d_in[3];   // [H,H]
    // d_in[4] = Wa_b: uniform per-b score shift -> softmax-invariant, dropped.

    float* out  = (float*)d_out;
    float* ctx  = out;             // [B,H]
    float* attn = out + NB * NH;   // [B,S]

    float*  v      = (float*)d_ws;                  // NB*NH floats
    float*  scores = v + NB * NH;                   // NB*NS floats
    double* denomD = (double*)(scores + NB * NS);   // NB doubles (8B-aligned)

    k1_v     <<<512,  256, 0, stream>>>(dec, Wa_w, v, denomD);
    k2_scores<<<2048, 512, 0, stream>>>(enc, v, scores, denomD);
    k3_out   <<<NB*8, 256, 0, stream>>>(enc, scores, ts, denomD, ctx, attn);
}